// Round 20
// baseline (356.381 us; speedup 1.0000x reference)
//
#include <hip/hip_runtime.h>
#include <hip/hip_fp16.h>

#define NN   50000      // nodes
#define NNP  50048      // padded to 128-multiple (391*128)
#define D0   300        // emb dim
#define K1   320        // GEMM1 K = embh row stride (640B = 10 lines)
#define N1   400        // layer-1 out dim
#define K2   448        // N1 padded to 64-multiple (= GEMM2 K)
#define N2   512        // layer-2 out dim
#define NBLK 196        // scan blocks: 196*256 = 50176 >= NN
#define EPB  4096       // edges per scatter chunk
#define NSL  8          // dst slices (XCD round-robin)
#define HEPB 8192       // edges per hist chunk

typedef __attribute__((ext_vector_type(8))) short bf16x8;
typedef __attribute__((ext_vector_type(4))) float f32x4;
typedef __attribute__((ext_vector_type(2))) float f32x2;
typedef __attribute__((ext_vector_type(4))) unsigned int u32x4;   // clang vector (NT-store ok)

__device__ __forceinline__ unsigned short f2bf(float x) {   // rn-even f32->bf16
    union { float f; unsigned u; } v; v.f = x;
    unsigned r = v.u + 0x7fffu + ((v.u >> 16) & 1u);
    return (unsigned short)(r >> 16);
}

// ---------------- fused: slice-partitioned edge histogram + weight transposes ----------------
// Hist blocks: (chunk, slice16). Slices 0-7 count dst in [s*6250,(s+1)*6250);
// slices 8-15 count src in [(s-8)*6250, ...). blockIdx&15 -> XCD round-robin gives each
// XCD an exclusive 25KB counter region (no cross-XCD atomic line ping-pong).
__global__ __launch_bounds__(256) void pre_kernel(const int* __restrict__ src,
                                                  const int* __restrict__ dst,
                                                  int* __restrict__ cnt_s,
                                                  int* __restrict__ cnt_d, int E, int nhist,
                                                  const float* __restrict__ W1,
                                                  const float* __restrict__ W2,
                                                  unsigned short* __restrict__ T1,
                                                  unsigned short* __restrict__ T2) {
    if ((int)blockIdx.x < nhist) {
        int slice = blockIdx.x & 15;
        int chunk = blockIdx.x >> 4;
        int base = chunk * HEPB;
        int lim = base + HEPB; if (lim > E) lim = E;
        if (slice < 8) {
            int lo = slice * (NN / 8), hi = lo + (NN / 8);
            for (int i = base + (int)threadIdx.x; i < lim; i += 256) {
                int d = dst[i];
                if (d >= lo && d < hi) atomicAdd(&cnt_d[d], 1);
            }
        } else {
            int lo = (slice - 8) * (NN / 8), hi = lo + (NN / 8);
            for (int i = base + (int)threadIdx.x; i < lim; i += 256) {
                int s = src[i];
                if (s >= lo && s < hi) atomicAdd(&cnt_s[s], 1);
            }
        }
        return;
    }
    int u = ((int)blockIdx.x - nhist) * 256 + threadIdx.x;
    if (u < K2 * K1) {                        // W1T [448][320]
        int n = u / K1, k = u - n * K1;
        float v = (n < N1 && k < D0) ? W1[k * N1 + n] : 0.f;
        T1[u] = f2bf(v);
    } else {
        u -= K2 * K1;
        if (u >= N2 * K2) return;             // W2T [512][448]
        int n = u / K2, k = u - n * K2;
        float v = (k < N1) ? W2[k * N2 + n] : 0.f;
        T2[u] = f2bf(v);
    }
}

// ---------------- block-local exclusive scan; bsum gets block totals ----------------
__global__ __launch_bounds__(256) void scan_blk_kernel(const int* __restrict__ cnt,
                                                       int* __restrict__ offs,
                                                       int* __restrict__ bsum) {
    __shared__ int sh[256];
    int t = threadIdx.x, g = blockIdx.x * 256 + t;
    int v = (g < NN) ? cnt[g] : 0;
    sh[t] = v;
    __syncthreads();
    for (int off = 1; off < 256; off <<= 1) {
        int u = (t >= off) ? sh[t - off] : 0;
        __syncthreads();
        sh[t] += u;
        __syncthreads();
    }
    if (g < NN) offs[g] = sh[t] - v;
    if (t == 255) bsum[blockIdx.x] = sh[255];
}

// ---------------- merged: scan block sums (redundant per block) + fixup + scales ----------
__global__ __launch_bounds__(256) void scan_fix_kernel(int* __restrict__ offs,
                                                       const int* __restrict__ bsum,
                                                       const int* __restrict__ cnt_s,
                                                       const int* __restrict__ cnt_d,
                                                       float* __restrict__ deg_s,
                                                       float* __restrict__ deg_d, int E) {
    __shared__ int sh[256];
    int t = threadIdx.x;
    int v = (t < NBLK) ? bsum[t] : 0;
    sh[t] = v;
    __syncthreads();
    for (int off = 1; off < 256; off <<= 1) {
        int u = (t >= off) ? sh[t - off] : 0;
        __syncthreads();
        sh[t] += u;
        __syncthreads();
    }
    int myboff = (blockIdx.x > 0) ? sh[blockIdx.x - 1] : 0;   // exclusive block offset
    int g = blockIdx.x * 256 + t;
    if (g < NN) {
        offs[g] += myboff;
        deg_s[g] = rsqrtf(fmaxf((float)cnt_s[g], 1.0f));
        deg_d[g] = rsqrtf(fmaxf((float)cnt_d[g], 1.0f));
    }
    if (g == NN) offs[NN] = E;
}

// ---------------- fused: dst-partitioned CSR scatter + emb f32->fp16 ----------------
__global__ __launch_bounds__(256) void scat_emb_kernel(
    const int* __restrict__ src, const int* __restrict__ dst,
    const int* __restrict__ offs, int* __restrict__ cursor,
    int* __restrict__ ssrc, int E, int nscat,
    const float* __restrict__ emb, const float* __restrict__ deg_s,
    __half* __restrict__ embh) {
    if ((int)blockIdx.x < nscat) {
        int slice = blockIdx.x & (NSL - 1);
        int chunk = blockIdx.x / NSL;
        int lo = slice * (NN / NSL), hi = lo + (NN / NSL);   // 6250-wide dst range
        int base = chunk * EPB;
        int lim = base + EPB; if (lim > E) lim = E;
#pragma unroll 4
        for (int i = base + (int)threadIdx.x; i < lim; i += 256) {
            int d = dst[i];
            if (d >= lo && d < hi) {
                int pos = atomicAdd(&cursor[d], 1);
                ssrc[offs[d] + pos] = src[i];
            }
        }
        return;
    }
    // embh: one uint2 (4 halfs) per thread, rows at stride K1=320 (cols >= 300 zero)
    int u = ((int)blockIdx.x - nscat) * 256 + threadIdx.x;
    const int CPR = K1 / 4;                   // 80 chunks per padded row
    if (u >= NN * CPR) return;
    int node = u / CPR, c = u - node * CPR;
    int f = 4 * c;
    __half h[4] = {__half(0.f), __half(0.f), __half(0.f), __half(0.f)};
    if (f < D0) {                             // D0%4==0 -> full float4 valid
        float sc = deg_s[node];
        float4 v = *(const float4*)(emb + (size_t)node * D0 + f);
        h[0] = __float2half(v.x * sc); h[1] = __float2half(v.y * sc);
        h[2] = __float2half(v.z * sc); h[3] = __float2half(v.w * sc);
    }
    *(uint2*)(embh + (size_t)node * K1 + f) = *(uint2*)h;
}

// ---------------- agg1: fp16 gather (8-unroll), bf16 out [NNP][320] ----------------
template <int KP>
__global__ __launch_bounds__(256) void agg_h_kernel(
    const __half* __restrict__ X, const int* __restrict__ offs,
    const int* __restrict__ ssrc, const float* __restrict__ nscale,
    unsigned short* __restrict__ O) {
    constexpr int D8 = KP / 8;        // 40 uint4 chunks per row (640B, line-aligned)
    int node = blockIdx.x * 4 + (threadIdx.x >> 6);
    if (node >= NNP) return;
    int l = threadIdx.x & 63;
    bool act = l < D8;
    const uint4* Xq = (const uint4*)X;

    float a[8] = {0.f, 0.f, 0.f, 0.f, 0.f, 0.f, 0.f, 0.f};

#define ACCUM(U) { const __half2* hp = (const __half2*)&(U);                        \
                   float2 f0 = __half22float2(hp[0]), f1 = __half22float2(hp[1]);   \
                   float2 f2 = __half22float2(hp[2]), f3 = __half22float2(hp[3]);   \
                   a[0] += f0.x; a[1] += f0.y; a[2] += f1.x; a[3] += f1.y;          \
                   a[4] += f2.x; a[5] += f2.y; a[6] += f3.x; a[7] += f3.y; }

    if (node < NN) {
        int j = offs[node], end = offs[node + 1];
        for (; j + 8 <= end; j += 8) {          // 8 independent 16B gathers in flight
            uint4 u0, u1, u2, u3, u4, u5, u6, u7;
            int s0 = ssrc[j + 0], s1 = ssrc[j + 1], s2 = ssrc[j + 2], s3 = ssrc[j + 3];
            int s4 = ssrc[j + 4], s5 = ssrc[j + 5], s6 = ssrc[j + 6], s7 = ssrc[j + 7];
            if (act) {
                u0 = Xq[(size_t)s0 * D8 + l]; u1 = Xq[(size_t)s1 * D8 + l];
                u2 = Xq[(size_t)s2 * D8 + l]; u3 = Xq[(size_t)s3 * D8 + l];
                u4 = Xq[(size_t)s4 * D8 + l]; u5 = Xq[(size_t)s5 * D8 + l];
                u6 = Xq[(size_t)s6 * D8 + l]; u7 = Xq[(size_t)s7 * D8 + l];
                ACCUM(u0); ACCUM(u1); ACCUM(u2); ACCUM(u3);
                ACCUM(u4); ACCUM(u5); ACCUM(u6); ACCUM(u7);
            }
        }
        for (; j + 2 <= end; j += 2) {
            int s0 = ssrc[j + 0], s1 = ssrc[j + 1];
            if (act) {
                uint4 u0 = Xq[(size_t)s0 * D8 + l];
                uint4 u1 = Xq[(size_t)s1 * D8 + l];
                ACCUM(u0); ACCUM(u1);
            }
        }
        for (; j < end; ++j) {
            int s0 = ssrc[j];
            if (act) { uint4 u0 = Xq[(size_t)s0 * D8 + l]; ACCUM(u0); }
        }
        float ns = nscale[node];
#pragma unroll
        for (int i = 0; i < 8; ++i) a[i] *= ns;
    }
#undef ACCUM

    if (act) {
        unsigned short hv[8];
#pragma unroll
        for (int i = 0; i < 8; ++i) hv[i] = f2bf(a[i]);   // zeros for pad rows
        __builtin_nontemporal_store(*(u32x4*)hv, (u32x4*)(O + (size_t)node * KP + 8 * l));
    }
}

// ---------------- agg2: fp8 gather, 2 nodes per wave (32-lane halves) ----------------
__global__ __launch_bounds__(256) void agg_q_kernel(
    const unsigned char* __restrict__ X, const int* __restrict__ offs,
    const int* __restrict__ ssrc, const float* __restrict__ nscale,
    unsigned short* __restrict__ O) {
    constexpr int D16 = 25;           // 16B chunks per fp8 row (400 bytes)
    constexpr int OS  = 28;           // 16-short store slots per out row (448)
    int w = threadIdx.x >> 6, l = threadIdx.x & 63;
    int half = l >> 5, sl = l & 31;
    int node = blockIdx.x * 8 + w * 2 + half;           // NNP % 8 == 0
    bool act = sl < D16;
    const uint4* Xq = (const uint4*)X;   // row stride 400B = 25 uint4

    float a[16];
#pragma unroll
    for (int i = 0; i < 16; ++i) a[i] = 0.f;

#define ACCQ(U) { f32x2 p;                                                          \
    p = __builtin_amdgcn_cvt_pk_f32_fp8((int)(U).x, false); a[0]+=p.x;  a[1]+=p.y;  \
    p = __builtin_amdgcn_cvt_pk_f32_fp8((int)(U).x, true);  a[2]+=p.x;  a[3]+=p.y;  \
    p = __builtin_amdgcn_cvt_pk_f32_fp8((int)(U).y, false); a[4]+=p.x;  a[5]+=p.y;  \
    p = __builtin_amdgcn_cvt_pk_f32_fp8((int)(U).y, true);  a[6]+=p.x;  a[7]+=p.y;  \
    p = __builtin_amdgcn_cvt_pk_f32_fp8((int)(U).z, false); a[8]+=p.x;  a[9]+=p.y;  \
    p = __builtin_amdgcn_cvt_pk_f32_fp8((int)(U).z, true);  a[10]+=p.x; a[11]+=p.y; \
    p = __builtin_amdgcn_cvt_pk_f32_fp8((int)(U).w, false); a[12]+=p.x; a[13]+=p.y; \
    p = __builtin_amdgcn_cvt_pk_f32_fp8((int)(U).w, true);  a[14]+=p.x; a[15]+=p.y; }

    if (node < NN) {
        int j = offs[node], end = offs[node + 1];
        for (; j + 8 <= end; j += 8) {
            uint4 u0, u1, u2, u3, u4, u5, u6, u7;
            int s0 = ssrc[j + 0], s1 = ssrc[j + 1], s2 = ssrc[j + 2], s3 = ssrc[j + 3];
            int s4 = ssrc[j + 4], s5 = ssrc[j + 5], s6 = ssrc[j + 6], s7 = ssrc[j + 7];
            if (act) {
                u0 = Xq[(size_t)s0 * D16 + sl]; u1 = Xq[(size_t)s1 * D16 + sl];
                u2 = Xq[(size_t)s2 * D16 + sl]; u3 = Xq[(size_t)s3 * D16 + sl];
                u4 = Xq[(size_t)s4 * D16 + sl]; u5 = Xq[(size_t)s5 * D16 + sl];
                u6 = Xq[(size_t)s6 * D16 + sl]; u7 = Xq[(size_t)s7 * D16 + sl];
                ACCQ(u0); ACCQ(u1); ACCQ(u2); ACCQ(u3);
                ACCQ(u4); ACCQ(u5); ACCQ(u6); ACCQ(u7);
            }
        }
        for (; j + 2 <= end; j += 2) {
            int s0 = ssrc[j + 0], s1 = ssrc[j + 1];
            if (act) {
                uint4 u0 = Xq[(size_t)s0 * D16 + sl];
                uint4 u1 = Xq[(size_t)s1 * D16 + sl];
                ACCQ(u0); ACCQ(u1);
            }
        }
        for (; j < end; ++j) {
            int s0 = ssrc[j];
            if (act) { uint4 u0 = Xq[(size_t)s0 * D16 + sl]; ACCQ(u0); }
        }
        float ns = nscale[node];
#pragma unroll
        for (int i = 0; i < 16; ++i) a[i] *= ns;
    }
#undef ACCQ

    if (node < NNP && sl < OS) {      // slots 25-27 store zeros (features 400..447)
        unsigned short hv[16];
#pragma unroll
        for (int i = 0; i < 16; ++i) hv[i] = f2bf(a[i]);
        unsigned short* dst = O + (size_t)node * K2 + 16 * sl;
        __builtin_nontemporal_store(*(u32x4*)hv, (u32x4*)dst);
        __builtin_nontemporal_store(*(u32x4*)(hv + 8), (u32x4*)(dst + 8));
    }
}

// ---------------- pure-bf16 MFMA GEMM, 128x64 tile, LDS-staged wide epilogue ----------------
// OMODE: 0 = f32 out via 32KB LDS tile + float4 NT stores; 1 = fp8 out via 8KB tile + uint4.
template <int OMODE>
__global__ __launch_bounds__(256) void gemm_bf16_kernel(
    const unsigned short* __restrict__ A, const unsigned short* __restrict__ BT,
    const float* __restrict__ bias, const float* __restrict__ rs,
    void* __restrict__ Cv, int nbn, int Kpad, int Nvalid, int Cld) {
    constexpr int LDS_SHORTS = (OMODE == 0) ? 16384 : 12288;
    __shared__ __align__(16) unsigned short lds[LDS_SHORTS];
    const int AOF = 0, BOF = 8192;

    int nwg = (int)gridDim.x, orig = (int)blockIdx.x;
    int q8 = nwg >> 3, r8 = nwg & 7;
    int xc = orig & 7, o8 = orig >> 3;
    int wg = (xc < r8 ? xc * (q8 + 1) : r8 * (q8 + 1) + (xc - r8) * q8) + o8;
    int bn = wg % nbn, bm = wg / nbn;
    int m0 = bm * 128, n0 = bn * 64;

    int t = threadIdx.x, l = t & 63, w = t >> 6;
    int wm = w >> 1, wn = w & 1;

    f32x4 acc[4][2] = {};

    for (int k0 = 0; k0 < Kpad; k0 += 64) {
#pragma unroll
        for (int j = 0; j < 4; ++j) {
            int c = j * 256 + t;
            int r = c >> 3, qs = c & 7;
            size_t goff = (size_t)(m0 + r) * Kpad + k0 + ((qs ^ (r & 7)) << 3);
            int lbase = (j * 256 + w * 64) * 8;
            __builtin_amdgcn_global_load_lds(
                (const __attribute__((address_space(1))) void*)(A + goff),
                (__attribute__((address_space(3))) void*)&lds[AOF + lbase], 16, 0, 0);
        }
#pragma unroll
        for (int j = 0; j < 2; ++j) {
            int c = j * 256 + t;
            int r = c >> 3, qs = c & 7;
            size_t goff = (size_t)(n0 + r) * Kpad + k0 + ((qs ^ (r & 7)) << 3);
            int lbase = (j * 256 + w * 64) * 8;
            __builtin_amdgcn_global_load_lds(
                (const __attribute__((address_space(1))) void*)(BT + goff),
                (__attribute__((address_space(3))) void*)&lds[BOF + lbase], 16, 0, 0);
        }
        __syncthreads();

#pragma unroll
        for (int ks = 0; ks < 2; ++ks) {
            bf16x8 bfr[2];
#pragma unroll
            for (int ni = 0; ni < 2; ++ni) {
                int n = wn * 32 + ni * 16 + (l & 15);
                int slot = ks * 4 + (l >> 4);
                int idx = n * 64 + ((slot ^ (n & 7)) << 3);
                bfr[ni] = *(const bf16x8*)&lds[BOF + idx];
            }
#pragma unroll
            for (int mi = 0; mi < 4; ++mi) {
                int m = wm * 64 + mi * 16 + (l & 15);
                int slot = ks * 4 + (l >> 4);
                int idx = m * 64 + ((slot ^ (m & 7)) << 3);
                bf16x8 afr = *(const bf16x8*)&lds[AOF + idx];
#pragma unroll
                for (int ni = 0; ni < 2; ++ni)
                    acc[mi][ni] = __builtin_amdgcn_mfma_f32_16x16x32_bf16(afr, bfr[ni], acc[mi][ni], 0, 0, 0);
            }
        }
        __syncthreads();
    }

    // ---- epilogue: acc -> LDS tile (128 x 64), then wide coalesced stores ----
    if (OMODE == 0) {
        float* ltile = (float*)lds;               // 128 x 64 f32 = 32KB
#pragma unroll
        for (int mi = 0; mi < 4; ++mi) {
            int rbase = wm * 64 + mi * 16 + ((l >> 4) << 2);
#pragma unroll
            for (int q = 0; q < 4; ++q) {
#pragma unroll
                for (int ni = 0; ni < 2; ++ni) {
                    int col = wn * 32 + ni * 16 + (l & 15);
                    ltile[(rbase + q) * 64 + col] = acc[mi][ni][q] + bias[n0 + col];
                }
            }
        }
        __syncthreads();
        const f32x4* lt4 = (const f32x4*)ltile;   // 2048 float4 (16 per row)
#pragma unroll
        for (int it = 0; it < 8; ++it) {
            int idx = it * 256 + t;
            int r = idx >> 4, c4 = idx & 15;
            int m = m0 + r;
            if (m < NN) {
                f32x4 v = lt4[idx];
                __builtin_nontemporal_store(
                    v, (f32x4*)((float*)Cv + (size_t)m * Cld + n0 + c4 * 4));
            }
        }
    } else {
        unsigned char* ltile = (unsigned char*)lds;   // 128 x 64 fp8 = 8KB
#pragma unroll
        for (int mi = 0; mi < 4; ++mi) {
            int rbase = wm * 64 + mi * 16 + ((l >> 4) << 2);
#pragma unroll
            for (int q = 0; q < 4; ++q) {
                int m = m0 + rbase + q;
                float scale = (m < NN) ? rs[m] : 0.f;
#pragma unroll
                for (int ni = 0; ni < 2; ++ni) {
                    int col = wn * 32 + ni * 16 + (l & 15);
                    float v = acc[mi][ni][q] + bias[n0 + col];
                    v = v >= 0.f ? v : 0.2f * v;
                    v *= scale;
                    int pk = __builtin_amdgcn_cvt_pk_fp8_f32(v, v, 0, false);
                    ltile[(rbase + q) * 64 + col] = (unsigned char)(pk & 0xff);
                }
            }
        }
        __syncthreads();
        const u32x4* lt4 = (const u32x4*)ltile;   // 512 uint4 (4 per row)
#pragma unroll
        for (int it = 0; it < 2; ++it) {
            int idx = it * 256 + t;
            int r = idx >> 2, ci = idx & 3;
            int m = m0 + r;
            int n = n0 + ci * 16;
            if (m < NN && n < Nvalid) {           // Nvalid % 16 == 0 -> chunk-granular
                u32x4 v = lt4[idx];
                __builtin_nontemporal_store(
                    v, (u32x4*)((unsigned char*)Cv + (size_t)m * Cld + n));
            }
        }
    }
}

extern "C" void kernel_launch(void* const* d_in, const int* in_sizes, int n_in,
                              void* d_out, int out_size, void* d_ws, size_t ws_size,
                              hipStream_t stream) {
    const float* emb = (const float*)d_in[0];
    const float* W1  = (const float*)d_in[1];
    const float* b1  = (const float*)d_in[2];
    const float* W2  = (const float*)d_in[3];
    const float* b2  = (const float*)d_in[4];
    const int*   src = (const int*)d_in[5];
    const int*   dst = (const int*)d_in[6];
    const int E = in_sizes[5];

    // ws layout (~78.4MB total):
    //   [0, 32.0MB)      A1 bf16 [NNP][320]
    //   [32.0, 76.9MB)   A2 bf16 [NNP][448]; embh fp16 [NN][320] (32MB) overlaps
    //                    A2's region but is dead (last read: agg1) before agg2 writes A2.
    //   [76.9MB, ...)    W1T bf16 [448][320], W2T bf16 [512][448]
    unsigned short* A1   = (unsigned short*)d_ws;
    unsigned short* A2   = A1 + (size_t)NNP * K1;
    __half*         embh = (__half*)A2;
    unsigned short* W1T  = A2 + (size_t)NNP * K2;
    unsigned short* W2T  = W1T + (size_t)K2 * K1;

    // d_out layout: h2 fp8 [NN][400] (20MB) | CSR + scales tail (~4.6MB).
    unsigned char* h2  = (unsigned char*)d_out;
    float*         out = (float*)d_out;
    char* tail = (char*)d_out + (size_t)NN * N1;       // fp8 = 1B/elem
    int* cnt_s  = (int*)tail;                // NN
    int* cnt_d  = cnt_s + NN;                // NN
    int* cursor = cnt_d + NN;                // NN   (memset covers these 3*NN)
    int* offs   = cursor + NN;               // NN+1
    int* bsum   = offs + NN + 1;             // NBLK
    int* ssrc   = bsum + NBLK;               // E
    float* deg_s = (float*)(ssrc + E);       // NN (out_s)
    float* deg_d = deg_s + NN;               // NN (in_s)

    hipMemsetAsync(cnt_s, 0, (size_t)(3 * NN) * sizeof(int), stream);

    // slice-partitioned hist + both weight transposes in one dispatch
    {
        int nhist = ((E + HEPB - 1) / HEPB) * 16;
        int nwt = (K2 * K1 + N2 * K2 + 255) / 256;
        pre_kernel<<<nhist + nwt, 256, 0, stream>>>(
            src, dst, cnt_s, cnt_d, E, nhist, W1, W2, W1T, W2T);
    }
    scan_blk_kernel<<<NBLK, 256, 0, stream>>>(cnt_d, offs, bsum);
    scan_fix_kernel<<<NBLK, 256, 0, stream>>>(offs, bsum, cnt_s, cnt_d, deg_s, deg_d, E);

    // dst-partitioned scatter + embh in one dispatch
    {
        int nscat = ((E + EPB - 1) / EPB) * NSL;
        int nembh = (NN * (K1 / 4) + 255) / 256;
        scat_emb_kernel<<<nscat + nembh, 256, 0, stream>>>(
            src, dst, offs, cursor, ssrc, E, nscat, emb, deg_s, embh);
    }

    // layer 1: A1[n] = bf16( in_s[n] * sum embh[s] )   (LD = KP = 320)
    agg_h_kernel<K1><<<NNP / 4, 256, 0, stream>>>(embh, offs, ssrc, deg_d, A1);

    // h2 = fp8( lrelu(A1 @ W1 + b1) * out_s );  7 n-tiles of 64 (n >= 400 masked)
    gemm_bf16_kernel<1><<<391 * 7, 256, 0, stream>>>(
        A1, W1T, b1, deg_s, h2, 7, K1, N1, N1);

    // layer 2: A2[n] = bf16( in_s[n] * sum h2[s] )   (fp8 gather, 2 nodes/wave)
    agg_q_kernel<<<NNP / 8, 256, 0, stream>>>(h2, offs, ssrc, deg_d, A2);

    // out = A2 @ W2 + b2   (f32, LDS-staged float4 NT stores);  8 n-tiles of 64
    gemm_bf16_kernel<0><<<391 * 8, 256, 0, stream>>>(
        A2, W2T, b2, nullptr, out, 8, K2, N2, N2);
}

// Round 21
// 353.519 us; speedup vs baseline: 1.0081x; 1.0081x over previous
//
#include <hip/hip_runtime.h>
#include <hip/hip_fp16.h>

#define NN   50000      // nodes
#define NNP  50048      // padded to 128-multiple (391*128)
#define D0   300        // emb dim
#define K1   320        // GEMM1 K = embh row stride (640B = 10 lines)
#define N1   400        // layer-1 out dim
#define K2   448        // N1 padded to 64-multiple (= GEMM2 K)
#define N2   512        // layer-2 out dim
#define NBLK 196        // scan blocks: 196*256 = 50176 >= NN
#define EPB  4096       // edges per scatter chunk
#define NSL  8          // dst slices (XCD round-robin)

typedef __attribute__((ext_vector_type(8))) short bf16x8;
typedef __attribute__((ext_vector_type(4))) float f32x4;
typedef __attribute__((ext_vector_type(2))) float f32x2;
typedef __attribute__((ext_vector_type(4))) unsigned int u32x4;   // clang vector (NT-store ok)

__device__ __forceinline__ unsigned short f2bf(float x) {   // rn-even f32->bf16
    union { float f; unsigned u; } v; v.f = x;
    unsigned r = v.u + 0x7fffu + ((v.u >> 16) & 1u);
    return (unsigned short)(r >> 16);
}

// ---------------- fused: edge histogram + both weight transposes (R19 form) ----------------
__global__ __launch_bounds__(256) void pre_kernel(const int* __restrict__ src,
                                                  const int* __restrict__ dst,
                                                  int* __restrict__ cnt_s,
                                                  int* __restrict__ cnt_d, int E,
                                                  const float* __restrict__ W1,
                                                  const float* __restrict__ W2,
                                                  unsigned short* __restrict__ T1,
                                                  unsigned short* __restrict__ T2) {
    int tid = blockIdx.x * 256 + threadIdx.x;
    if (tid < E) {
        atomicAdd(&cnt_s[src[tid]], 1);
        atomicAdd(&cnt_d[dst[tid]], 1);
        return;
    }
    int u = tid - E;
    if (u < K2 * K1) {                        // W1T [448][320]
        int n = u / K1, k = u - n * K1;
        float v = (n < N1 && k < D0) ? W1[k * N1 + n] : 0.f;
        T1[u] = f2bf(v);
    } else {
        u -= K2 * K1;
        if (u >= N2 * K2) return;             // W2T [512][448]
        int n = u / K2, k = u - n * K2;
        float v = (k < N1) ? W2[k * N2 + n] : 0.f;
        T2[u] = f2bf(v);
    }
}

// ---------------- block-local exclusive scan; bsum gets block totals ----------------
__global__ __launch_bounds__(256) void scan_blk_kernel(const int* __restrict__ cnt,
                                                       int* __restrict__ offs,
                                                       int* __restrict__ bsum) {
    __shared__ int sh[256];
    int t = threadIdx.x, g = blockIdx.x * 256 + t;
    int v = (g < NN) ? cnt[g] : 0;
    sh[t] = v;
    __syncthreads();
    for (int off = 1; off < 256; off <<= 1) {
        int u = (t >= off) ? sh[t - off] : 0;
        __syncthreads();
        sh[t] += u;
        __syncthreads();
    }
    if (g < NN) offs[g] = sh[t] - v;
    if (t == 255) bsum[blockIdx.x] = sh[255];
}

// ---------------- merged: scan block sums (redundant per block) + fixup + scales ----------
__global__ __launch_bounds__(256) void scan_fix_kernel(int* __restrict__ offs,
                                                       const int* __restrict__ bsum,
                                                       const int* __restrict__ cnt_s,
                                                       const int* __restrict__ cnt_d,
                                                       float* __restrict__ deg_s,
                                                       float* __restrict__ deg_d, int E) {
    __shared__ int sh[256];
    int t = threadIdx.x;
    int v = (t < NBLK) ? bsum[t] : 0;
    sh[t] = v;
    __syncthreads();
    for (int off = 1; off < 256; off <<= 1) {
        int u = (t >= off) ? sh[t - off] : 0;
        __syncthreads();
        sh[t] += u;
        __syncthreads();
    }
    int myboff = (blockIdx.x > 0) ? sh[blockIdx.x - 1] : 0;   // exclusive block offset
    int g = blockIdx.x * 256 + t;
    if (g < NN) {
        offs[g] += myboff;
        deg_s[g] = rsqrtf(fmaxf((float)cnt_s[g], 1.0f));
        deg_d[g] = rsqrtf(fmaxf((float)cnt_d[g], 1.0f));
    }
    if (g == NN) offs[NN] = E;
}

// ---------------- fused: dst-partitioned CSR scatter + emb f32->fp16 ----------------
// Scatter blocks: (chunk, slice) pairs; block with slice x commits only edges whose dst is
// in [x*6250,(x+1)*6250) -> each XCD's ssrc writes land in a contiguous ~400KB L2-resident
// region (kills cross-XCD line-thrash write amplification, R19: -16us).
__global__ __launch_bounds__(256) void scat_emb_kernel(
    const int* __restrict__ src, const int* __restrict__ dst,
    const int* __restrict__ offs, int* __restrict__ cursor,
    int* __restrict__ ssrc, int E, int nscat,
    const float* __restrict__ emb, const float* __restrict__ deg_s,
    __half* __restrict__ embh) {
    if ((int)blockIdx.x < nscat) {
        int slice = blockIdx.x & (NSL - 1);
        int chunk = blockIdx.x / NSL;
        int lo = slice * (NN / NSL), hi = lo + (NN / NSL);   // 6250-wide dst range
        int base = chunk * EPB;
        int lim = base + EPB; if (lim > E) lim = E;
#pragma unroll 4
        for (int i = base + (int)threadIdx.x; i < lim; i += 256) {
            int d = dst[i];
            if (d >= lo && d < hi) {
                int pos = atomicAdd(&cursor[d], 1);
                ssrc[offs[d] + pos] = src[i];
            }
        }
        return;
    }
    // embh: one uint2 (4 halfs) per thread, rows at stride K1=320 (cols >= 300 zero)
    int u = ((int)blockIdx.x - nscat) * 256 + threadIdx.x;
    const int CPR = K1 / 4;                   // 80 chunks per padded row
    if (u >= NN * CPR) return;
    int node = u / CPR, c = u - node * CPR;
    int f = 4 * c;
    __half h[4] = {__half(0.f), __half(0.f), __half(0.f), __half(0.f)};
    if (f < D0) {                             // D0%4==0 -> full float4 valid
        float sc = deg_s[node];
        float4 v = *(const float4*)(emb + (size_t)node * D0 + f);
        h[0] = __float2half(v.x * sc); h[1] = __float2half(v.y * sc);
        h[2] = __float2half(v.z * sc); h[3] = __float2half(v.w * sc);
    }
    *(uint2*)(embh + (size_t)node * K1 + f) = *(uint2*)h;
}

// ---------------- agg1: fp16 gather (8-unroll), bf16 out [NNP][320] ----------------
template <int KP>
__global__ __launch_bounds__(256) void agg_h_kernel(
    const __half* __restrict__ X, const int* __restrict__ offs,
    const int* __restrict__ ssrc, const float* __restrict__ nscale,
    unsigned short* __restrict__ O) {
    constexpr int D8 = KP / 8;        // 40 uint4 chunks per row (640B, line-aligned)
    int node = blockIdx.x * 4 + (threadIdx.x >> 6);
    if (node >= NNP) return;
    int l = threadIdx.x & 63;
    bool act = l < D8;
    const uint4* Xq = (const uint4*)X;

    float a[8] = {0.f, 0.f, 0.f, 0.f, 0.f, 0.f, 0.f, 0.f};

#define ACCUM(U) { const __half2* hp = (const __half2*)&(U);                        \
                   float2 f0 = __half22float2(hp[0]), f1 = __half22float2(hp[1]);   \
                   float2 f2 = __half22float2(hp[2]), f3 = __half22float2(hp[3]);   \
                   a[0] += f0.x; a[1] += f0.y; a[2] += f1.x; a[3] += f1.y;          \
                   a[4] += f2.x; a[5] += f2.y; a[6] += f3.x; a[7] += f3.y; }

    if (node < NN) {
        int j = offs[node], end = offs[node + 1];
        for (; j + 8 <= end; j += 8) {          // 8 independent 16B gathers in flight
            uint4 u0, u1, u2, u3, u4, u5, u6, u7;
            int s0 = ssrc[j + 0], s1 = ssrc[j + 1], s2 = ssrc[j + 2], s3 = ssrc[j + 3];
            int s4 = ssrc[j + 4], s5 = ssrc[j + 5], s6 = ssrc[j + 6], s7 = ssrc[j + 7];
            if (act) {
                u0 = Xq[(size_t)s0 * D8 + l]; u1 = Xq[(size_t)s1 * D8 + l];
                u2 = Xq[(size_t)s2 * D8 + l]; u3 = Xq[(size_t)s3 * D8 + l];
                u4 = Xq[(size_t)s4 * D8 + l]; u5 = Xq[(size_t)s5 * D8 + l];
                u6 = Xq[(size_t)s6 * D8 + l]; u7 = Xq[(size_t)s7 * D8 + l];
                ACCUM(u0); ACCUM(u1); ACCUM(u2); ACCUM(u3);
                ACCUM(u4); ACCUM(u5); ACCUM(u6); ACCUM(u7);
            }
        }
        for (; j + 2 <= end; j += 2) {
            int s0 = ssrc[j + 0], s1 = ssrc[j + 1];
            if (act) {
                uint4 u0 = Xq[(size_t)s0 * D8 + l];
                uint4 u1 = Xq[(size_t)s1 * D8 + l];
                ACCUM(u0); ACCUM(u1);
            }
        }
        for (; j < end; ++j) {
            int s0 = ssrc[j];
            if (act) { uint4 u0 = Xq[(size_t)s0 * D8 + l]; ACCUM(u0); }
        }
        float ns = nscale[node];
#pragma unroll
        for (int i = 0; i < 8; ++i) a[i] *= ns;
    }
#undef ACCUM

    if (act) {
        unsigned short hv[8];
#pragma unroll
        for (int i = 0; i < 8; ++i) hv[i] = f2bf(a[i]);   // zeros for pad rows
        __builtin_nontemporal_store(*(u32x4*)hv, (u32x4*)(O + (size_t)node * KP + 8 * l));
    }
}

// ---------------- agg2: fp8 gather, 2 nodes per wave (32-lane halves) ----------------
__global__ __launch_bounds__(256) void agg_q_kernel(
    const unsigned char* __restrict__ X, const int* __restrict__ offs,
    const int* __restrict__ ssrc, const float* __restrict__ nscale,
    unsigned short* __restrict__ O) {
    constexpr int D16 = 25;           // 16B chunks per fp8 row (400 bytes)
    constexpr int OS  = 28;           // 16-short store slots per out row (448)
    int w = threadIdx.x >> 6, l = threadIdx.x & 63;
    int half = l >> 5, sl = l & 31;
    int node = blockIdx.x * 8 + w * 2 + half;           // NNP % 8 == 0
    bool act = sl < D16;
    const uint4* Xq = (const uint4*)X;   // row stride 400B = 25 uint4

    float a[16];
#pragma unroll
    for (int i = 0; i < 16; ++i) a[i] = 0.f;

#define ACCQ(U) { f32x2 p;                                                          \
    p = __builtin_amdgcn_cvt_pk_f32_fp8((int)(U).x, false); a[0]+=p.x;  a[1]+=p.y;  \
    p = __builtin_amdgcn_cvt_pk_f32_fp8((int)(U).x, true);  a[2]+=p.x;  a[3]+=p.y;  \
    p = __builtin_amdgcn_cvt_pk_f32_fp8((int)(U).y, false); a[4]+=p.x;  a[5]+=p.y;  \
    p = __builtin_amdgcn_cvt_pk_f32_fp8((int)(U).y, true);  a[6]+=p.x;  a[7]+=p.y;  \
    p = __builtin_amdgcn_cvt_pk_f32_fp8((int)(U).z, false); a[8]+=p.x;  a[9]+=p.y;  \
    p = __builtin_amdgcn_cvt_pk_f32_fp8((int)(U).z, true);  a[10]+=p.x; a[11]+=p.y; \
    p = __builtin_amdgcn_cvt_pk_f32_fp8((int)(U).w, false); a[12]+=p.x; a[13]+=p.y; \
    p = __builtin_amdgcn_cvt_pk_f32_fp8((int)(U).w, true);  a[14]+=p.x; a[15]+=p.y; }

    if (node < NN) {
        int j = offs[node], end = offs[node + 1];
        for (; j + 8 <= end; j += 8) {
            uint4 u0, u1, u2, u3, u4, u5, u6, u7;
            int s0 = ssrc[j + 0], s1 = ssrc[j + 1], s2 = ssrc[j + 2], s3 = ssrc[j + 3];
            int s4 = ssrc[j + 4], s5 = ssrc[j + 5], s6 = ssrc[j + 6], s7 = ssrc[j + 7];
            if (act) {
                u0 = Xq[(size_t)s0 * D16 + sl]; u1 = Xq[(size_t)s1 * D16 + sl];
                u2 = Xq[(size_t)s2 * D16 + sl]; u3 = Xq[(size_t)s3 * D16 + sl];
                u4 = Xq[(size_t)s4 * D16 + sl]; u5 = Xq[(size_t)s5 * D16 + sl];
                u6 = Xq[(size_t)s6 * D16 + sl]; u7 = Xq[(size_t)s7 * D16 + sl];
                ACCQ(u0); ACCQ(u1); ACCQ(u2); ACCQ(u3);
                ACCQ(u4); ACCQ(u5); ACCQ(u6); ACCQ(u7);
            }
        }
        for (; j + 2 <= end; j += 2) {
            int s0 = ssrc[j + 0], s1 = ssrc[j + 1];
            if (act) {
                uint4 u0 = Xq[(size_t)s0 * D16 + sl];
                uint4 u1 = Xq[(size_t)s1 * D16 + sl];
                ACCQ(u0); ACCQ(u1);
            }
        }
        for (; j < end; ++j) {
            int s0 = ssrc[j];
            if (act) { uint4 u0 = Xq[(size_t)s0 * D16 + sl]; ACCQ(u0); }
        }
        float ns = nscale[node];
#pragma unroll
        for (int i = 0; i < 16; ++i) a[i] *= ns;
    }
#undef ACCQ

    if (node < NNP && sl < OS) {      // slots 25-27 store zeros (features 400..447)
        unsigned short hv[16];
#pragma unroll
        for (int i = 0; i < 16; ++i) hv[i] = f2bf(a[i]);
        unsigned short* dst = O + (size_t)node * K2 + 16 * sl;
        __builtin_nontemporal_store(*(u32x4*)hv, (u32x4*)dst);
        __builtin_nontemporal_store(*(u32x4*)(hv + 8), (u32x4*)(dst + 8));
    }
}

// ---------------- pure-bf16 MFMA GEMM, 128x64 tile, LDS-staged wide epilogue ----------------
// OMODE: 0 = f32 out via 32KB LDS tile + float4 NT stores; 1 = fp8 out via 8KB tile + uint4.
template <int OMODE>
__global__ __launch_bounds__(256) void gemm_bf16_kernel(
    const unsigned short* __restrict__ A, const unsigned short* __restrict__ BT,
    const float* __restrict__ bias, const float* __restrict__ rs,
    void* __restrict__ Cv, int nbn, int Kpad, int Nvalid, int Cld) {
    constexpr int LDS_SHORTS = (OMODE == 0) ? 16384 : 12288;
    __shared__ __align__(16) unsigned short lds[LDS_SHORTS];
    const int AOF = 0, BOF = 8192;

    int nwg = (int)gridDim.x, orig = (int)blockIdx.x;
    int q8 = nwg >> 3, r8 = nwg & 7;
    int xc = orig & 7, o8 = orig >> 3;
    int wg = (xc < r8 ? xc * (q8 + 1) : r8 * (q8 + 1) + (xc - r8) * q8) + o8;
    int bn = wg % nbn, bm = wg / nbn;
    int m0 = bm * 128, n0 = bn * 64;

    int t = threadIdx.x, l = t & 63, w = t >> 6;
    int wm = w >> 1, wn = w & 1;

    f32x4 acc[4][2] = {};

    for (int k0 = 0; k0 < Kpad; k0 += 64) {
#pragma unroll
        for (int j = 0; j < 4; ++j) {
            int c = j * 256 + t;
            int r = c >> 3, qs = c & 7;
            size_t goff = (size_t)(m0 + r) * Kpad + k0 + ((qs ^ (r & 7)) << 3);
            int lbase = (j * 256 + w * 64) * 8;
            __builtin_amdgcn_global_load_lds(
                (const __attribute__((address_space(1))) void*)(A + goff),
                (__attribute__((address_space(3))) void*)&lds[AOF + lbase], 16, 0, 0);
        }
#pragma unroll
        for (int j = 0; j < 2; ++j) {
            int c = j * 256 + t;
            int r = c >> 3, qs = c & 7;
            size_t goff = (size_t)(n0 + r) * Kpad + k0 + ((qs ^ (r & 7)) << 3);
            int lbase = (j * 256 + w * 64) * 8;
            __builtin_amdgcn_global_load_lds(
                (const __attribute__((address_space(1))) void*)(BT + goff),
                (__attribute__((address_space(3))) void*)&lds[BOF + lbase], 16, 0, 0);
        }
        __syncthreads();

#pragma unroll
        for (int ks = 0; ks < 2; ++ks) {
            bf16x8 bfr[2];
#pragma unroll
            for (int ni = 0; ni < 2; ++ni) {
                int n = wn * 32 + ni * 16 + (l & 15);
                int slot = ks * 4 + (l >> 4);
                int idx = n * 64 + ((slot ^ (n & 7)) << 3);
                bfr[ni] = *(const bf16x8*)&lds[BOF + idx];
            }
#pragma unroll
            for (int mi = 0; mi < 4; ++mi) {
                int m = wm * 64 + mi * 16 + (l & 15);
                int slot = ks * 4 + (l >> 4);
                int idx = m * 64 + ((slot ^ (m & 7)) << 3);
                bf16x8 afr = *(const bf16x8*)&lds[AOF + idx];
#pragma unroll
                for (int ni = 0; ni < 2; ++ni)
                    acc[mi][ni] = __builtin_amdgcn_mfma_f32_16x16x32_bf16(afr, bfr[ni], acc[mi][ni], 0, 0, 0);
            }
        }
        __syncthreads();
    }

    // ---- epilogue: acc -> LDS tile (128 x 64), then wide coalesced stores ----
    if (OMODE == 0) {
        float* ltile = (float*)lds;               // 128 x 64 f32 = 32KB
#pragma unroll
        for (int mi = 0; mi < 4; ++mi) {
            int rbase = wm * 64 + mi * 16 + ((l >> 4) << 2);
#pragma unroll
            for (int q = 0; q < 4; ++q) {
#pragma unroll
                for (int ni = 0; ni < 2; ++ni) {
                    int col = wn * 32 + ni * 16 + (l & 15);
                    ltile[(rbase + q) * 64 + col] = acc[mi][ni][q] + bias[n0 + col];
                }
            }
        }
        __syncthreads();
        const f32x4* lt4 = (const f32x4*)ltile;   // 2048 float4 (16 per row)
#pragma unroll
        for (int it = 0; it < 8; ++it) {
            int idx = it * 256 + t;
            int r = idx >> 4, c4 = idx & 15;
            int m = m0 + r;
            if (m < NN) {
                f32x4 v = lt4[idx];
                __builtin_nontemporal_store(
                    v, (f32x4*)((float*)Cv + (size_t)m * Cld + n0 + c4 * 4));
            }
        }
    } else {
        unsigned char* ltile = (unsigned char*)lds;   // 128 x 64 fp8 = 8KB
#pragma unroll
        for (int mi = 0; mi < 4; ++mi) {
            int rbase = wm * 64 + mi * 16 + ((l >> 4) << 2);
#pragma unroll
            for (int q = 0; q < 4; ++q) {
                int m = m0 + rbase + q;
                float scale = (m < NN) ? rs[m] : 0.f;
#pragma unroll
                for (int ni = 0; ni < 2; ++ni) {
                    int col = wn * 32 + ni * 16 + (l & 15);
                    float v = acc[mi][ni][q] + bias[n0 + col];
                    v = v >= 0.f ? v : 0.2f * v;
                    v *= scale;
                    int pk = __builtin_amdgcn_cvt_pk_fp8_f32(v, v, 0, false);
                    ltile[(rbase + q) * 64 + col] = (unsigned char)(pk & 0xff);
                }
            }
        }
        __syncthreads();
        const u32x4* lt4 = (const u32x4*)ltile;   // 512 uint4 (4 per row)
#pragma unroll
        for (int it = 0; it < 2; ++it) {
            int idx = it * 256 + t;
            int r = idx >> 2, ci = idx & 3;
            int m = m0 + r;
            int n = n0 + ci * 16;
            if (m < NN && n < Nvalid) {           // Nvalid % 16 == 0 -> chunk-granular
                u32x4 v = lt4[idx];
                __builtin_nontemporal_store(
                    v, (u32x4*)((unsigned char*)Cv + (size_t)m * Cld + n));
            }
        }
    }
}

extern "C" void kernel_launch(void* const* d_in, const int* in_sizes, int n_in,
                              void* d_out, int out_size, void* d_ws, size_t ws_size,
                              hipStream_t stream) {
    const float* emb = (const float*)d_in[0];
    const float* W1  = (const float*)d_in[1];
    const float* b1  = (const float*)d_in[2];
    const float* W2  = (const float*)d_in[3];
    const float* b2  = (const float*)d_in[4];
    const int*   src = (const int*)d_in[5];
    const int*   dst = (const int*)d_in[6];
    const int E = in_sizes[5];

    // ws layout (~78.4MB total):
    //   [0, 32.0MB)      A1 bf16 [NNP][320]
    //   [32.0, 76.9MB)   A2 bf16 [NNP][448]; embh fp16 [NN][320] (32MB) overlaps
    //                    A2's region but is dead (last read: agg1) before agg2 writes A2.
    //   [76.9MB, ...)    W1T bf16 [448][320], W2T bf16 [512][448]
    unsigned short* A1   = (unsigned short*)d_ws;
    unsigned short* A2   = A1 + (size_t)NNP * K1;
    __half*         embh = (__half*)A2;
    unsigned short* W1T  = A2 + (size_t)NNP * K2;
    unsigned short* W2T  = W1T + (size_t)K2 * K1;

    // d_out layout: h2 fp8 [NN][400] (20MB) | CSR + scales tail (~4.6MB).
    unsigned char* h2  = (unsigned char*)d_out;
    float*         out = (float*)d_out;
    char* tail = (char*)d_out + (size_t)NN * N1;       // fp8 = 1B/elem
    int* cnt_s  = (int*)tail;                // NN
    int* cnt_d  = cnt_s + NN;                // NN
    int* cursor = cnt_d + NN;                // NN   (memset covers these 3*NN)
    int* offs   = cursor + NN;               // NN+1
    int* bsum   = offs + NN + 1;             // NBLK
    int* ssrc   = bsum + NBLK;               // E
    float* deg_s = (float*)(ssrc + E);       // NN (out_s)
    float* deg_d = deg_s + NN;               // NN (in_s)

    hipMemsetAsync(cnt_s, 0, (size_t)(3 * NN) * sizeof(int), stream);

    // hist + both weight transposes in one dispatch (simple form: R20's slicing was neutral)
    {
        int total = E + K2 * K1 + N2 * K2;
        pre_kernel<<<(total + 255) / 256, 256, 0, stream>>>(
            src, dst, cnt_s, cnt_d, E, W1, W2, W1T, W2T);
    }
    scan_blk_kernel<<<NBLK, 256, 0, stream>>>(cnt_d, offs, bsum);
    scan_fix_kernel<<<NBLK, 256, 0, stream>>>(offs, bsum, cnt_s, cnt_d, deg_s, deg_d, E);

    // dst-partitioned scatter + embh in one dispatch
    {
        int nscat = ((E + EPB - 1) / EPB) * NSL;
        int nembh = (NN * (K1 / 4) + 255) / 256;
        scat_emb_kernel<<<nscat + nembh, 256, 0, stream>>>(
            src, dst, offs, cursor, ssrc, E, nscat, emb, deg_s, embh);
    }

    // layer 1: A1[n] = bf16( in_s[n] * sum embh[s] )   (LD = KP = 320)
    agg_h_kernel<K1><<<NNP / 4, 256, 0, stream>>>(embh, offs, ssrc, deg_d, A1);

    // h2 = fp8( lrelu(A1 @ W1 + b1) * out_s );  7 n-tiles of 64 (n >= 400 masked)
    gemm_bf16_kernel<1><<<391 * 7, 256, 0, stream>>>(
        A1, W1T, b1, deg_s, h2, 7, K1, N1, N1);

    // layer 2: A2[n] = bf16( in_s[n] * sum h2[s] )   (fp8 gather, 2 nodes/wave)
    agg_q_kernel<<<NNP / 8, 256, 0, stream>>>(h2, offs, ssrc, deg_d, A2);

    // out = A2 @ W2 + b2   (f32, LDS-staged float4 NT stores);  8 n-tiles of 64
    gemm_bf16_kernel<0><<<391 * 8, 256, 0, stream>>>(
        A2, W2T, b2, nullptr, out, 8, K2, N2, N2);
}